// Round 7
// baseline (104.101 us; speedup 1.0000x reference)
//
#include <hip/hip_runtime.h>
#include <math.h>

#define BATCH 64
#define SEQL  2048
#define EMB   300
#define NROWS (BATCH * SEQL)
#define NV4   (NROWS * 75)   // 300/4 float4 per row
#define U     16
#define CHUNK 32             // output steps per chain
#define WARM  64             // speculative warm-up steps (multiple of U)
#define NCHUNK (SEQL / CHUNK)   // 64 == wave size (used by reduce)

typedef float floatx4 __attribute__((ext_vector_type(4)));

static __device__ __forceinline__ float fast_rcp(float x) {
#if __has_builtin(__builtin_amdgcn_rcpf)
    return __builtin_amdgcn_rcpf(x);
#else
    return 1.0f / x;
#endif
}

static __device__ __forceinline__ float fast_exp2(float x) {
#if __has_builtin(__builtin_amdgcn_exp2f)
    return __builtin_amdgcn_exp2f(x);
#else
    return exp2f(x);
#endif
}

// Kernel 1: time-major xg float4[t][b] = {-L2E*(xWi+bi), -L2E*(xWf+bf),
//           -2L2E*(xWg+bg), -L2E*(xWo+bo)}   (gate order i,f,g,o)
// 2 rows per wave-iteration interleaved for load-level parallelism.
__global__ void __launch_bounds__(256) proj_kernel(
    const float* __restrict__ x, const float* __restrict__ Wih,
    const float* __restrict__ bih, const float* __restrict__ bhh,
    float4* __restrict__ xg)
{
    const float L2E = 1.4426950408889634f;
    const int lane = threadIdx.x & 63;
    const int wid  = threadIdx.x >> 6;

    float4 w0[4], w1[4];
    float  bs[4];
#pragma unroll
    for (int k = 0; k < 4; ++k) {
        const float4* wr = (const float4*)(Wih + k * EMB);
        w0[k] = wr[lane];
        w1[k] = (lane < 11) ? wr[64 + lane] : make_float4(0.f, 0.f, 0.f, 0.f);
        bs[k] = bih[k] + bhh[k];
    }

    const int stride  = gridDim.x * 4;
    for (int row = blockIdx.x * 4 + wid; row < NROWS; row += 2 * stride) {
        const int rowB = row + stride;
        const bool hasB = rowB < NROWS;
        const float4* xrA = (const float4*)(x + (size_t)row * EMB);
        const float4* xrB = (const float4*)(x + (size_t)(hasB ? rowB : row) * EMB);
        // issue all 4 independent loads up front
        float4 a0 = xrA[lane];
        float4 b0 = xrB[lane];
        float4 a1 = (lane < 11) ? xrA[64 + lane] : make_float4(0.f, 0.f, 0.f, 0.f);
        float4 b1 = (lane < 11) ? xrB[64 + lane] : make_float4(0.f, 0.f, 0.f, 0.f);

        float accA[4], accB[4];
#pragma unroll
        for (int k = 0; k < 4; ++k) {
            float a, bv;
            a  = a0.x * w0[k].x; a = fmaf(a0.y, w0[k].y, a);
            a  = fmaf(a0.z, w0[k].z, a); a = fmaf(a0.w, w0[k].w, a);
            a  = fmaf(a1.x, w1[k].x, a); a = fmaf(a1.y, w1[k].y, a);
            a  = fmaf(a1.z, w1[k].z, a); a = fmaf(a1.w, w1[k].w, a);
            accA[k] = a;
            bv = b0.x * w0[k].x; bv = fmaf(b0.y, w0[k].y, bv);
            bv = fmaf(b0.z, w0[k].z, bv); bv = fmaf(b0.w, w0[k].w, bv);
            bv = fmaf(b1.x, w1[k].x, bv); bv = fmaf(b1.y, w1[k].y, bv);
            bv = fmaf(b1.z, w1[k].z, bv); bv = fmaf(b1.w, w1[k].w, bv);
            accB[k] = bv;
        }
#pragma unroll
        for (int m = 32; m >= 1; m >>= 1) {
#pragma unroll
            for (int k = 0; k < 4; ++k) {
                accA[k] += __shfl_xor(accA[k], m, 64);
                accB[k] += __shfl_xor(accB[k], m, 64);
            }
        }
        if (lane == 0) {
            {
                int t = row & (SEQL - 1), bb = row >> 11;
                xg[t * BATCH + bb] = make_float4(
                    -L2E * (accA[0] + bs[0]), -L2E * (accA[1] + bs[1]),
                    -2.f * L2E * (accA[2] + bs[2]), -L2E * (accA[3] + bs[3]));
            }
            if (hasB) {
                int t = rowB & (SEQL - 1), bb = rowB >> 11;
                xg[t * BATCH + bb] = make_float4(
                    -L2E * (accB[0] + bs[0]), -L2E * (accB[1] + bs[1]),
                    -2.f * L2E * (accB[2] + bs[2]), -L2E * (accB[3] + bs[3]));
            }
        }
    }
}

// Kernel 2: speculative chunked LSTM scan + chunk-local online softmax partials.
// sched_barrier(0) pins the prefetch loads BEFORE the compute (the compiler
// otherwise sinks them to their uses — R2-R5 ran at ~230cyc/step, one L2
// round-trip per step, VGPR_Count=40 proving the buffers never materialized).
__global__ void __launch_bounds__(64, 1) lstm_scan_kernel(
    const float4* __restrict__ xg, const int* __restrict__ slen,
    const float* __restrict__ Whh, float* __restrict__ score,
    float2* __restrict__ part)
{
    const float L2E = 1.4426950408889634f;
    const float K2  = -2.f * L2E;
    const int b = threadIdx.x;
    const int k = blockIdx.x;
    const float wi = -L2E * Whh[0];
    const float wf = -L2E * Whh[1];
    const float wg = K2   * Whh[2];
    const float wo = -L2E * Whh[3];
    const bool masked = slen[b] > 0;

    const int cstart = k * CHUNK;
    const int tstart = (cstart >= WARM) ? (cstart - WARM) : 0;
    const int nch    = (cstart + CHUNK - tstart) / U;   // 2,4,6,6,... (even)

    float h = 0.f, c = 0.f;
    float m = -1e30f, sum = 0.f;

    float4 bufA[U], bufB[U];
#pragma unroll
    for (int u = 0; u < U; ++u) bufA[u] = xg[(tstart + u) * BATCH + b];
    __builtin_amdgcn_sched_barrier(0);

#define STEP(g4, T_) do {                                                  \
    float gi = fast_rcp(1.f + fast_exp2(fmaf(h, wi, (g4).x)));             \
    float gf = fast_rcp(1.f + fast_exp2(fmaf(h, wf, (g4).y)));             \
    float go = fast_rcp(1.f + fast_exp2(fmaf(h, wo, (g4).w)));             \
    float gg = fmaf(2.f, fast_rcp(1.f + fast_exp2(fmaf(h, wg, (g4).z))), -1.f); \
    float ig  = gi * gg;                                                   \
    float f2  = K2 * gf;                                                   \
    float ig2 = K2 * ig;                                                   \
    float targ = fmaf(f2, c, ig2);          /* = -2L2E*c_new, parallel */  \
    c = fmaf(gf, c, ig);                                                   \
    float tc = fmaf(2.f, fast_rcp(1.f + fast_exp2(targ)), -1.f);           \
    h = go * tc;                                                           \
    if (do_store) {                                                        \
        score[(T_) * BATCH + b] = h;                                       \
        if (!((T_) == 0 && masked)) {                                      \
            float mn = fmaxf(m, h);                                        \
            sum = fmaf(sum, fast_exp2((m - mn) * L2E),                     \
                       fast_exp2((h - mn) * L2E));                         \
            m = mn;                                                        \
        }                                                                  \
    }                                                                      \
} while (0)

    for (int ich = 0; ich < nch; ich += 2) {
        int tA = tstart + ich * U;
        int tB = tA + U;
#pragma unroll
        for (int u = 0; u < U; ++u)
            bufB[u] = xg[(tB + u) * BATCH + b];
        __builtin_amdgcn_sched_barrier(0);
        {
            const bool do_store = (tA >= cstart);
#pragma unroll
            for (int u = 0; u < U; ++u) STEP(bufA[u], tA + u);
        }
        if (ich + 2 < nch) {
#pragma unroll
            for (int u = 0; u < U; ++u)
                bufA[u] = xg[(tB + U + u) * BATCH + b];
        }
        __builtin_amdgcn_sched_barrier(0);
        {
            const bool do_store = (tB >= cstart);
#pragma unroll
            for (int u = 0; u < U; ++u) STEP(bufB[u], tB + u);
        }
    }
#undef STEP

    part[b * NCHUNK + k] = make_float2(m, sum);
}

// Kernel 2b: combine NCHUNK(=64) partials per batch into softmax stats.
__global__ void __launch_bounds__(64) reduce_kernel(
    const float2* __restrict__ part, float* __restrict__ stats)
{
    const float L2E = 1.4426950408889634f;
    const int b = blockIdx.x;
    const int l = threadIdx.x;       // chunk id, NCHUNK == 64

    float2 p = part[b * NCHUNK + l];

    float M = p.x;
#pragma unroll
    for (int s = 32; s >= 1; s >>= 1) M = fmaxf(M, __shfl_xor(M, s, 64));

    float sum = p.y * fast_exp2((p.x - M) * L2E);
#pragma unroll
    for (int s = 32; s >= 1; s >>= 1) sum += __shfl_xor(sum, s, 64);

    if (l == 0) {
        stats[b] = M;
        stats[BATCH + b] = fast_rcp(sum);
    }
}

// Kernel 3: out[b,t,:] = softmax-weight(b,t) * x[b,t,:]; finalize fused.
// 2-way unrolled grid-stride for MLP; NT stores keep x resident in L2/L3.
__global__ void __launch_bounds__(256) scale_kernel(
    const float4* __restrict__ x4, const float* __restrict__ score,
    const float* __restrict__ stats, const int* __restrict__ slen,
    float4* __restrict__ out4)
{
    const float L2E = 1.4426950408889634f;
    const int stride = gridDim.x * blockDim.x;
    for (int idx = blockIdx.x * blockDim.x + threadIdx.x; idx < NV4;
         idx += 2 * stride) {
        const int idx2 = idx + stride;
        const bool has2 = idx2 < NV4;

        unsigned row  = (unsigned)idx / 75u;
        unsigned row2 = (unsigned)(has2 ? idx2 : idx) / 75u;
        // issue both x loads + both score loads before any math
        float4 v  = x4[idx];
        float4 v2 = x4[has2 ? idx2 : idx];
        unsigned bb  = row >> 11,  t  = row & 2047u;
        unsigned bb2 = row2 >> 11, t2 = row2 & 2047u;
        float s  = score[t  * BATCH + bb];
        float s2 = score[t2 * BATCH + bb2];

        float a = fast_exp2((s - stats[bb]) * L2E) * stats[BATCH + bb];
        if (t == 0u && slen[bb] > 0) a = 0.f;
        floatx4 r = {a * v.x, a * v.y, a * v.z, a * v.w};
        __builtin_nontemporal_store(r, (floatx4*)&out4[idx]);

        if (has2) {
            float a2 = fast_exp2((s2 - stats[bb2]) * L2E) * stats[BATCH + bb2];
            if (t2 == 0u && slen[bb2] > 0) a2 = 0.f;
            floatx4 r2 = {a2 * v2.x, a2 * v2.y, a2 * v2.z, a2 * v2.w};
            __builtin_nontemporal_store(r2, (floatx4*)&out4[idx2]);
        }
    }
}

extern "C" void kernel_launch(void* const* d_in, const int* in_sizes, int n_in,
                              void* d_out, int out_size, void* d_ws, size_t ws_size,
                              hipStream_t stream)
{
    const float* x    = (const float*)d_in[0];
    const int*   slen = (const int*)d_in[1];
    const float* Wih  = (const float*)d_in[2];
    const float* Whh  = (const float*)d_in[3];
    const float* bih  = (const float*)d_in[4];
    const float* bhh  = (const float*)d_in[5];
    float* out = (float*)d_out;

    char* ws = (char*)d_ws;
    float4* xg    = (float4*)ws;                                  // 2 MB, [t][b] float4
    float*  score = (float*)(ws + (size_t)NROWS * 16);            // 512 KB, [t][b]
    float*  stats = (float*)(ws + (size_t)NROWS * 20);            // 2*64 floats
    float2* part  = (float2*)(ws + (size_t)NROWS * 20 + 1024);    // 64*64 float2 = 32 KB

    proj_kernel<<<4096, 256, 0, stream>>>(x, Wih, bih, bhh, xg);
    lstm_scan_kernel<<<NCHUNK, 64, 0, stream>>>(xg, slen, Whh, score, part);
    reduce_kernel<<<BATCH, 64, 0, stream>>>(part, stats);
    scale_kernel<<<4096, 256, 0, stream>>>((const float4*)x, score, stats, slen,
                                           (float4*)out);
}